// Round 1
// baseline (762.902 us; speedup 1.0000x reference)
//
#include <hip/hip_runtime.h>

#define S_LEN  2048
#define BATCH  2
#define DMODEL 1024
#define NHEADS 16
#define DHEAD  64
#define DFF    4096
#define MROWS  (S_LEN*BATCH)   // 4096

typedef __attribute__((ext_vector_type(8))) short bf16x8;
typedef __attribute__((ext_vector_type(4))) float f32x4;
typedef __attribute__((ext_vector_type(4))) short s16x4;

#define NEG_BIG (-3.0e38f)

__device__ __forceinline__ short f2bf(float f){
  unsigned u = __float_as_uint(f);
  u += 0x7fffu + ((u >> 16) & 1u);
  return (short)(u >> 16);
}

// ---------------- cast f32 -> bf16 ----------------
__global__ __launch_bounds__(256) void cast_kernel(const float* __restrict__ in,
                                                   short* __restrict__ out, int n){
  int i = (blockIdx.x * 256 + threadIdx.x) * 4;
  if (i >= n) return;
  f32x4 v = *(const f32x4*)(in + i);
  s16x4 o;
  o[0] = f2bf(v[0]); o[1] = f2bf(v[1]); o[2] = f2bf(v[2]); o[3] = f2bf(v[3]);
  *(s16x4*)(out + i) = o;
}

// ---------------- GEMM: C[M][N] = A[M][K] * Bt[N][K]^T ----------------
// block 256 thr (4 waves), 64x64 tile, BK=32, mfma 16x16x32 bf16
__global__ __launch_bounds__(256) void gemm_bt(const short* __restrict__ A,
                                               const short* __restrict__ Bt,
                                               float* __restrict__ Cf,
                                               short* __restrict__ Cb,
                                               int M, int N, int K){
  __shared__ short As[64][32];
  __shared__ short Bs[64][32];
  const int t = threadIdx.x;
  const int lane = t & 63, w = t >> 6;
  const int m0 = blockIdx.y * 64, n0 = blockIdx.x * 64;
  const int wm = (w >> 1) * 32, wn = (w & 1) * 32;
  const int lr = lane & 15, lg = lane >> 4;

  f32x4 acc[2][2] = {};

  const int sr = t >> 2, sg = (t & 3) * 8;
  const short* Ap = A  + (size_t)(m0 + sr) * K + sg;
  const short* Bp = Bt + (size_t)(n0 + sr) * K + sg;

  for (int k0 = 0; k0 < K; k0 += 32){
    __syncthreads();
    *(bf16x8*)&As[sr][sg] = *(const bf16x8*)(Ap + k0);
    *(bf16x8*)&Bs[sr][sg] = *(const bf16x8*)(Bp + k0);
    __syncthreads();
    bf16x8 a0 = *(const bf16x8*)&As[wm      + lr][lg * 8];
    bf16x8 a1 = *(const bf16x8*)&As[wm + 16 + lr][lg * 8];
    bf16x8 b0 = *(const bf16x8*)&Bs[wn      + lr][lg * 8];
    bf16x8 b1 = *(const bf16x8*)&Bs[wn + 16 + lr][lg * 8];
    acc[0][0] = __builtin_amdgcn_mfma_f32_16x16x32_bf16(a0, b0, acc[0][0], 0, 0, 0);
    acc[0][1] = __builtin_amdgcn_mfma_f32_16x16x32_bf16(a0, b1, acc[0][1], 0, 0, 0);
    acc[1][0] = __builtin_amdgcn_mfma_f32_16x16x32_bf16(a1, b0, acc[1][0], 0, 0, 0);
    acc[1][1] = __builtin_amdgcn_mfma_f32_16x16x32_bf16(a1, b1, acc[1][1], 0, 0, 0);
  }

  for (int mi = 0; mi < 2; mi++){
    for (int ni = 0; ni < 2; ni++){
      int row = m0 + wm + mi * 16 + lg * 4;
      int col = n0 + wn + ni * 16 + lr;
      for (int r = 0; r < 4; r++){
        float v = acc[mi][ni][r];
        if (Cf) Cf[(size_t)(row + r) * N + col] = v;
        if (Cb) Cb[(size_t)(row + r) * N + col] = f2bf(v);
      }
    }
  }
}

// ---------------- fused causal flash attention ----------------
// grid (S/64, B*NH), block 256 (4 waves x 16 query rows)
__global__ __launch_bounds__(256) void attn_kernel(const short* __restrict__ Qh,
                                                   const short* __restrict__ Kh,
                                                   const short* __restrict__ Vh,
                                                   short* __restrict__ AV){
  __shared__ short Ks[64][64];
  __shared__ short Vst[64][64];   // transposed: [dh][j]
  __shared__ short Ps[4][16][64];
  const int t = threadIdx.x, lane = t & 63, w = t >> 6;
  const int bx = blockIdx.x;
  const int hb = blockIdx.y;
  const int b = hb >> 4, n = hb & 15;
  const size_t headoff = (size_t)n * DHEAD;
  const int q0 = bx * 64 + w * 16;
  const int lr = lane & 15, lg = lane >> 4;

  // Q fragments (16 rows x 64 k), k = kk*32 + 8*lg + i
  bf16x8 aq[2];
  {
    const short* qp = Qh + ((size_t)(q0 + lr) * BATCH + b) * DMODEL + headoff + lg * 8;
    aq[0] = *(const bf16x8*)(qp);
    aq[1] = *(const bf16x8*)(qp + 32);
  }

  f32x4 acc[4] = {};
  float m_run[4], l_run[4];
  for (int r = 0; r < 4; r++){ m_run[r] = NEG_BIG; l_run[r] = 0.f; }

  const int njt = bx + 1;
  for (int jt = 0; jt < njt; jt++){
    const int j0 = jt * 64;
    __syncthreads();
    {
      // stage K tile [64 j][64 d]
      int j = t >> 2, g = (t & 3) * 16;
      const short* kp = Kh + ((size_t)(j0 + j) * BATCH + b) * DMODEL + headoff + g;
      *(bf16x8*)&Ks[j][g]     = *(const bf16x8*)(kp);
      *(bf16x8*)&Ks[j][g + 8] = *(const bf16x8*)(kp + 8);
      // stage V transposed [64 dh][64 j]
      int jv = t & 63, dq = (t >> 6) * 16;
      const short* vp = Vh + ((size_t)(j0 + jv) * BATCH + b) * DMODEL + headoff + dq;
      bf16x8 v0 = *(const bf16x8*)(vp);
      bf16x8 v1 = *(const bf16x8*)(vp + 8);
      for (int e = 0; e < 8; e++){
        Vst[dq + e][jv]     = v0[e];
        Vst[dq + 8 + e][jv] = v1[e];
      }
    }
    __syncthreads();

    // scores: S[16 x 64]
    f32x4 s[4];
    for (int nf = 0; nf < 4; nf++){
      f32x4 z = {};
      for (int kk = 0; kk < 2; kk++){
        bf16x8 bk = *(const bf16x8*)&Ks[nf * 16 + lr][kk * 32 + lg * 8];
        z = __builtin_amdgcn_mfma_f32_16x16x32_bf16(aq[kk], bk, z, 0, 0, 0);
      }
      s[nf] = z;
    }

    // scale + causal mask + row max
    float m_tile[4];
    for (int r = 0; r < 4; r++){
      int i_glob = q0 + lg * 4 + r;
      float mx = NEG_BIG;
      for (int nf = 0; nf < 4; nf++){
        int j_glob = j0 + nf * 16 + lr;
        float v = s[nf][r] * 0.125f;
        if (j_glob > i_glob) v = NEG_BIG;
        s[nf][r] = v;
        mx = fmaxf(mx, v);
      }
      for (int msk = 1; msk < 16; msk <<= 1) mx = fmaxf(mx, __shfl_xor(mx, msk, 64));
      m_tile[r] = mx;
    }
    float corr[4];
    for (int r = 0; r < 4; r++){
      float mn = fmaxf(m_run[r], m_tile[r]);
      corr[r] = expf(m_run[r] - mn);
      m_run[r] = mn;
    }
    // P = exp(S - m), row sums, update l
    for (int r = 0; r < 4; r++){
      float rs = 0.f;
      for (int nf = 0; nf < 4; nf++){
        float p = expf(s[nf][r] - m_run[r]);
        s[nf][r] = p;
        rs += p;
      }
      for (int msk = 1; msk < 16; msk <<= 1) rs += __shfl_xor(rs, msk, 64);
      l_run[r] = l_run[r] * corr[r] + rs;
    }
    // rescale accumulator
    for (int df = 0; df < 4; df++)
      for (int r = 0; r < 4; r++) acc[df][r] *= corr[r];
    // P -> bf16 -> LDS (row-major [16][64] per wave)
    for (int r = 0; r < 4; r++)
      for (int nf = 0; nf < 4; nf++)
        Ps[w][lg * 4 + r][nf * 16 + lr] = f2bf(s[nf][r]);
    __syncthreads();
    // PV: acc += P(16x64) * V(64x64)
    for (int kk = 0; kk < 2; kk++){
      bf16x8 pa = *(const bf16x8*)&Ps[w][lr][kk * 32 + lg * 8];
      for (int df = 0; df < 4; df++){
        bf16x8 bv = *(const bf16x8*)&Vst[df * 16 + lr][kk * 32 + lg * 8];
        acc[df] = __builtin_amdgcn_mfma_f32_16x16x32_bf16(pa, bv, acc[df], 0, 0, 0);
      }
    }
  }

  // write attn_vec (bf16)
  for (int df = 0; df < 4; df++){
    for (int r = 0; r < 4; r++){
      int i_glob = q0 + lg * 4 + r;
      AV[((size_t)i_glob * BATCH + b) * DMODEL + headoff + df * 16 + lr] =
          f2bf(acc[df][r] / l_run[r]);
    }
  }
}

// ---------------- LayerNorm: out = g*(xa+xb - mu)*rstd + b ----------------
__global__ __launch_bounds__(256) void ln_kernel(const float* __restrict__ xa,
                                                 const float* __restrict__ xb,
                                                 const float* __restrict__ gamma,
                                                 const float* __restrict__ beta,
                                                 float* __restrict__ outF,
                                                 short* __restrict__ outB){
  __shared__ float red[4];
  const int row = blockIdx.x, t = threadIdx.x;
  const size_t base = (size_t)row * DMODEL + t * 4;
  f32x4 a  = *(const f32x4*)(xa + base);
  f32x4 bb = *(const f32x4*)(xb + base);
  f32x4 x;
  for (int e = 0; e < 4; e++) x[e] = a[e] + bb[e];
  float sum = x[0] + x[1] + x[2] + x[3];
  for (int m = 1; m < 64; m <<= 1) sum += __shfl_xor(sum, m, 64);
  if ((t & 63) == 0) red[t >> 6] = sum;
  __syncthreads();
  float mu = (red[0] + red[1] + red[2] + red[3]) * (1.f / DMODEL);
  float sq = 0.f;
  for (int e = 0; e < 4; e++){ float d = x[e] - mu; sq += d * d; }
  for (int m = 1; m < 64; m <<= 1) sq += __shfl_xor(sq, m, 64);
  __syncthreads();
  if ((t & 63) == 0) red[t >> 6] = sq;
  __syncthreads();
  float var = (red[0] + red[1] + red[2] + red[3]) * (1.f / DMODEL);
  float rstd = rsqrtf(var + 1e-5f);
  f32x4 g  = *(const f32x4*)(gamma + t * 4);
  f32x4 be = *(const f32x4*)(beta + t * 4);
  for (int e = 0; e < 4; e++){
    float y = g[e] * (x[e] - mu) * rstd + be[e];
    if (outF) outF[base + e] = y;
    if (outB) outB[base + e] = f2bf(y);
  }
}

// ---------------- KL reduction ----------------
__global__ __launch_bounds__(256) void kl_kernel(const float* __restrict__ mean,
                                                 const float* __restrict__ stdv,
                                                 int n, double* acc){
  __shared__ double red[4];
  double local = 0.0;
  int stride = gridDim.x * 256;
  for (int i = blockIdx.x * 256 + threadIdx.x; i < n; i += stride){
    float m = mean[i], s = stdv[i];
    local += (double)(m * m) - 2.0 * (double)s + (double)expf(2.f * s);
  }
  for (int msk = 1; msk < 64; msk <<= 1) local += __shfl_xor(local, msk, 64);
  const int t = threadIdx.x;
  if ((t & 63) == 0) red[t >> 6] = local;
  __syncthreads();
  if (t == 0) atomicAdd(acc, red[0] + red[1] + red[2] + red[3]);
}

__global__ void kl_final(const double* acc, float* out){
  // attn_kl = sum0 / 2 / (4*1024*1024); ff_kl = sum1 / 2 / (4096*2048)
  out[0] = (float)(acc[0] / 8388608.0 + acc[1] / 16777216.0);
}

// ---------------- launch ----------------
extern "C" void kernel_launch(void* const* d_in, const int* in_sizes, int n_in,
                              void* d_out, int out_size, void* d_ws, size_t ws_size,
                              hipStream_t stream){
  (void)in_sizes; (void)n_in; (void)out_size; (void)ws_size;
  const float* dec = (const float*)d_in[0];
  const float* qm  = (const float*)d_in[2];
  const float* km  = (const float*)d_in[3];
  const float* vm  = (const float*)d_in[4];
  const float* qs  = (const float*)d_in[5];
  const float* ks  = (const float*)d_in[6];
  const float* vs  = (const float*)d_in[7];
  const float* om  = (const float*)d_in[8];
  const float* os_ = (const float*)d_in[9];
  const float* g1  = (const float*)d_in[10];
  const float* b1  = (const float*)d_in[11];
  const float* w1m = (const float*)d_in[12];
  const float* w2m = (const float*)d_in[13];
  const float* w1s = (const float*)d_in[14];
  const float* w2s = (const float*)d_in[15];
  const float* g2  = (const float*)d_in[16];
  const float* b2  = (const float*)d_in[17];
  float* out = (float*)d_out;

  char* ws = (char*)d_ws;
  size_t off = 0;
  auto alloc = [&](size_t bytes) -> char* {
    char* p = ws + off;
    off += (bytes + 255) & ~(size_t)255;
    return p;
  };
  short* Xb  = (short*)alloc((size_t)MROWS * DMODEL * 2);  // X bf16; reused as h bf16
  short* Wq  = (short*)alloc((size_t)DMODEL * DMODEL * 2);
  short* Wk  = (short*)alloc((size_t)DMODEL * DMODEL * 2);
  short* Wv  = (short*)alloc((size_t)DMODEL * DMODEL * 2);
  short* W1  = (short*)alloc((size_t)DFF * DMODEL * 2);
  short* W2  = (short*)alloc((size_t)DMODEL * DFF * 2);
  short* Qh  = (short*)alloc((size_t)MROWS * DMODEL * 2);
  short* Kh  = (short*)alloc((size_t)MROWS * DMODEL * 2);
  short* Vh  = (short*)alloc((size_t)MROWS * DMODEL * 2);
  short* AVb = (short*)alloc((size_t)MROWS * DMODEL * 2);
  float* tmpF = (float*)alloc((size_t)MROWS * DMODEL * 4); // attn_out then l2
  float* hF   = (float*)alloc((size_t)MROWS * DMODEL * 4);
  double* acc = (double*)alloc(256);
  short* L1 = Qh;  // reuse Qh..AVb region (exactly 33.55 MB) after attention

  hipMemsetAsync(acc, 0, 16, stream);

  // casts
  cast_kernel<<<MROWS * DMODEL / 1024, 256, 0, stream>>>(dec, Xb, MROWS * DMODEL);
  cast_kernel<<<DMODEL * DMODEL / 1024, 256, 0, stream>>>(qm, Wq, DMODEL * DMODEL);
  cast_kernel<<<DMODEL * DMODEL / 1024, 256, 0, stream>>>(km, Wk, DMODEL * DMODEL);
  cast_kernel<<<DMODEL * DMODEL / 1024, 256, 0, stream>>>(vm, Wv, DMODEL * DMODEL);
  cast_kernel<<<DFF * DMODEL / 1024, 256, 0, stream>>>(w1m, W1, DFF * DMODEL);
  cast_kernel<<<DMODEL * DFF / 1024, 256, 0, stream>>>(w2m, W2, DMODEL * DFF);

  // QKV projections
  dim3 gp(DMODEL / 64, MROWS / 64);
  gemm_bt<<<gp, 256, 0, stream>>>(Xb, Wq, nullptr, Qh, MROWS, DMODEL, DMODEL);
  gemm_bt<<<gp, 256, 0, stream>>>(Xb, Wk, nullptr, Kh, MROWS, DMODEL, DMODEL);
  gemm_bt<<<gp, 256, 0, stream>>>(Xb, Wv, nullptr, Vh, MROWS, DMODEL, DMODEL);

  // attention
  attn_kernel<<<dim3(S_LEN / 64, BATCH * NHEADS), 256, 0, stream>>>(Qh, Kh, Vh, AVb);

  // attn output projection (bug-faithful: uses value_mean)
  gemm_bt<<<gp, 256, 0, stream>>>(AVb, Wv, tmpF, nullptr, MROWS, DMODEL, DMODEL);

  // LN1: h = LN(dec + attn_out) -> hF (f32) + Xb (bf16)
  ln_kernel<<<MROWS, 256, 0, stream>>>(dec, tmpF, g1, b1, hF, Xb);

  // FF
  gemm_bt<<<dim3(DFF / 64, MROWS / 64), 256, 0, stream>>>(Xb, W1, nullptr, L1, MROWS, DFF, DMODEL);
  gemm_bt<<<dim3(DMODEL / 64, MROWS / 64), 256, 0, stream>>>(L1, W2, tmpF, nullptr, MROWS, DMODEL, DFF);

  // LN2 -> final out
  ln_kernel<<<MROWS, 256, 0, stream>>>(hF, tmpF, g2, b2, out, nullptr);

  // KL
  kl_kernel<<<1024, 256, 0, stream>>>(qm, qs, DMODEL * DMODEL, acc);
  kl_kernel<<<1024, 256, 0, stream>>>(km, ks, DMODEL * DMODEL, acc);
  kl_kernel<<<1024, 256, 0, stream>>>(vm, vs, DMODEL * DMODEL, acc);
  kl_kernel<<<1024, 256, 0, stream>>>(om, os_, DMODEL * DMODEL, acc);
  kl_kernel<<<1024, 256, 0, stream>>>(w1m, w1s, DFF * DMODEL, acc + 1);
  kl_kernel<<<1024, 256, 0, stream>>>(w2m, w2s, DMODEL * DFF, acc + 1);
  kl_final<<<1, 1, 0, stream>>>(acc, out + (size_t)MROWS * DMODEL);
}

// Round 3
// 591.944 us; speedup vs baseline: 1.2888x; 1.2888x over previous
//
#include <hip/hip_runtime.h>

#define S_LEN  2048
#define BATCH  2
#define DMODEL 1024
#define NHEADS 16
#define DHEAD  64
#define DFF    4096
#define MROWS  (S_LEN*BATCH)   // 4096
#define QKVN   3072

typedef __attribute__((ext_vector_type(8))) short bf16x8;
typedef __attribute__((ext_vector_type(4))) float f32x4;
typedef __attribute__((ext_vector_type(4))) short s16x4;

#define NEG_BIG (-3.0e38f)
#define SCALE_LOG2 (0.125f * 1.4426950408889634f)

__device__ __forceinline__ short f2bf(float f){
  unsigned u = __float_as_uint(f);
  u += 0x7fffu + ((u >> 16) & 1u);
  return (short)(u >> 16);
}

__device__ __forceinline__ void gload16(const void* gptr, void* lptr){
  __builtin_amdgcn_global_load_lds(
      (const __attribute__((address_space(1))) unsigned int*)gptr,
      (__attribute__((address_space(3))) unsigned int*)lptr,
      16, 0, 0);
}

// ---------------- cast f32 -> bf16 ----------------
__global__ __launch_bounds__(256) void cast_kernel(const float* __restrict__ in,
                                                   short* __restrict__ out, int n){
  int i = (blockIdx.x * 256 + threadIdx.x) * 4;
  if (i >= n) return;
  f32x4 v = *(const f32x4*)(in + i);
  s16x4 o;
  o[0] = f2bf(v[0]); o[1] = f2bf(v[1]); o[2] = f2bf(v[2]); o[3] = f2bf(v[3]);
  *(s16x4*)(out + i) = o;
}

// ---------------- GEMM: C[M][N] = A[M][K] * Bt[N][K]^T ----------------
// m97 structure: 128x128 tile, BK=32, 8 waves (512 thr), global_load_lds w=16
__global__ __launch_bounds__(512) void gemm_bt(const short* __restrict__ A,
                                               const short* __restrict__ Bt,
                                               float* __restrict__ Cf,
                                               short* __restrict__ Cb,
                                               int M, int N, int K){
  __shared__ short As[128][32];
  __shared__ short Bs[128][32];
  const int t = threadIdx.x;
  const int lane = t & 63, w = t >> 6;
  const int m0 = blockIdx.y * 128, n0 = blockIdx.x * 128;
  const int wm = (w & 3) * 32, wn = (w >> 2) * 64;
  const int lr = lane & 15, lg = lane >> 4;

  f32x4 acc[2][4] = {};

  const short* Ap = A  + (size_t)(m0 + (t >> 2)) * K + (t & 3) * 8;
  const short* Bp = Bt + (size_t)(n0 + (t >> 2)) * K + (t & 3) * 8;
  char* ldsA = (char*)(&As[0][0]) + w * 1024;
  char* ldsB = (char*)(&Bs[0][0]) + w * 1024;

  for (int k0 = 0; k0 < K; k0 += 32){
    gload16(Ap + k0, ldsA);
    gload16(Bp + k0, ldsB);
    __syncthreads();
    bf16x8 a0 = *(const bf16x8*)&As[wm      + lr][lg * 8];
    bf16x8 a1 = *(const bf16x8*)&As[wm + 16 + lr][lg * 8];
    bf16x8 b0 = *(const bf16x8*)&Bs[wn      + lr][lg * 8];
    bf16x8 b1 = *(const bf16x8*)&Bs[wn + 16 + lr][lg * 8];
    bf16x8 b2 = *(const bf16x8*)&Bs[wn + 32 + lr][lg * 8];
    bf16x8 b3 = *(const bf16x8*)&Bs[wn + 48 + lr][lg * 8];
    acc[0][0] = __builtin_amdgcn_mfma_f32_16x16x32_bf16(a0, b0, acc[0][0], 0, 0, 0);
    acc[0][1] = __builtin_amdgcn_mfma_f32_16x16x32_bf16(a0, b1, acc[0][1], 0, 0, 0);
    acc[0][2] = __builtin_amdgcn_mfma_f32_16x16x32_bf16(a0, b2, acc[0][2], 0, 0, 0);
    acc[0][3] = __builtin_amdgcn_mfma_f32_16x16x32_bf16(a0, b3, acc[0][3], 0, 0, 0);
    acc[1][0] = __builtin_amdgcn_mfma_f32_16x16x32_bf16(a1, b0, acc[1][0], 0, 0, 0);
    acc[1][1] = __builtin_amdgcn_mfma_f32_16x16x32_bf16(a1, b1, acc[1][1], 0, 0, 0);
    acc[1][2] = __builtin_amdgcn_mfma_f32_16x16x32_bf16(a1, b2, acc[1][2], 0, 0, 0);
    acc[1][3] = __builtin_amdgcn_mfma_f32_16x16x32_bf16(a1, b3, acc[1][3], 0, 0, 0);
    __syncthreads();
  }

  for (int mi = 0; mi < 2; mi++){
    for (int ni = 0; ni < 4; ni++){
      int row = m0 + wm + mi * 16 + lg * 4;
      int col = n0 + wn + ni * 16 + lr;
      for (int r = 0; r < 4; r++){
        float v = acc[mi][ni][r];
        if (Cf) Cf[(size_t)(row + r) * N + col] = v;
        if (Cb) Cb[(size_t)(row + r) * N + col] = f2bf(v);
      }
    }
  }
}

// ---------------- fused causal flash attention ----------------
// grid (16, B*NH): each block does q-tiles bx and 31-bx (uniform 33 K-tiles)
// block 256 (4 waves x 16 q-rows), KVBLK=64, XOR-swizzled LDS
__global__ __launch_bounds__(256) void attn_kernel(const short* __restrict__ QKV,
                                                   short* __restrict__ AV){
  __shared__ short Ks[64][64];
  __shared__ short Vst[64][64];   // transposed: [dh][j], swizzled
  __shared__ short Ps[4][16][64];
  const int t = threadIdx.x, lane = t & 63, w = t >> 6;
  const int hb = blockIdx.y;
  const int b = hb >> 4, n = hb & 15;
  const int lr = lane & 15, lg = lane >> 4;

  for (int half = 0; half < 2; half++){
    const int qt = half ? (31 - (int)blockIdx.x) : (int)blockIdx.x;
    const int q0 = qt * 64 + w * 16;

    // Q fragments (16 rows x 64 k)
    bf16x8 aq[2];
    {
      const short* qp = QKV + ((size_t)(q0 + lr) * BATCH + b) * QKVN + n * DHEAD + lg * 8;
      aq[0] = *(const bf16x8*)(qp);
      aq[1] = *(const bf16x8*)(qp + 32);
    }

    f32x4 acc[4] = {};
    float m_run[4], l_run[4];
    for (int r = 0; r < 4; r++){ m_run[r] = NEG_BIG; l_run[r] = 0.f; }

    const int njt = qt + 1;
    for (int jt = 0; jt < njt; jt++){
      const int j0 = jt * 64;
      __syncthreads();
      {
        // stage K tile [64 j][64 d], swizzled units
        int j = t >> 2, u0 = (t & 3) * 2;
        const short* kp = QKV + ((size_t)(j0 + j) * BATCH + b) * QKVN + DMODEL + n * DHEAD + u0 * 8;
        *(bf16x8*)&Ks[j][(u0 ^ (j & 7)) * 8]       = *(const bf16x8*)(kp);
        *(bf16x8*)&Ks[j][((u0 + 1) ^ (j & 7)) * 8] = *(const bf16x8*)(kp + 8);
        // stage V transposed [64 dh][64 j], swizzled
        int jv = t & 63, dq = (t >> 6) * 16;
        const short* vp = QKV + ((size_t)(j0 + jv) * BATCH + b) * QKVN + 2 * DMODEL + n * DHEAD + dq;
        bf16x8 v0 = *(const bf16x8*)(vp);
        bf16x8 v1 = *(const bf16x8*)(vp + 8);
        int uj = jv >> 3, jl = jv & 7;
        for (int e = 0; e < 8; e++){
          int sc = (((uj ^ e) << 3) | jl);
          Vst[dq + e][sc]     = v0[e];
          Vst[dq + 8 + e][sc] = v1[e];
        }
      }
      __syncthreads();

      // scores: S[16 x 64]
      f32x4 s[4];
      __builtin_amdgcn_s_setprio(1);
      for (int nf = 0; nf < 4; nf++){
        f32x4 z = {};
        for (int kk = 0; kk < 2; kk++){
          int row = nf * 16 + lr;
          bf16x8 bk = *(const bf16x8*)&Ks[row][((kk * 4 + lg) ^ (lr & 7)) * 8];
          z = __builtin_amdgcn_mfma_f32_16x16x32_bf16(aq[kk], bk, z, 0, 0, 0);
        }
        s[nf] = z;
      }
      __builtin_amdgcn_s_setprio(0);

      // scale (log2 domain) + causal mask + row max
      for (int r = 0; r < 4; r++){
        int i_glob = q0 + lg * 4 + r;
        float mx = NEG_BIG;
        for (int nf = 0; nf < 4; nf++){
          int j_glob = j0 + nf * 16 + lr;
          float v = s[nf][r] * SCALE_LOG2;
          if (j_glob > i_glob) v = NEG_BIG;
          s[nf][r] = v;
          mx = fmaxf(mx, v);
        }
        for (int msk = 1; msk < 16; msk <<= 1) mx = fmaxf(mx, __shfl_xor(mx, msk, 64));
        float mn = fmaxf(m_run[r], mx);
        float corr = __builtin_exp2f(m_run[r] - mn);
        m_run[r] = mn;
        l_run[r] *= corr;
        for (int df = 0; df < 4; df++) acc[df][r] *= corr;
      }
      // P = exp2(S - m), row sums, store to swizzled Ps
      for (int r = 0; r < 4; r++){
        int prow = lg * 4 + r;
        float rs = 0.f;
        for (int nf = 0; nf < 4; nf++){
          float p = __builtin_exp2f(s[nf][r] - m_run[r]);
          rs += p;
          int u = (nf * 2) + (lr >> 3);
          Ps[w][prow][((u ^ (prow & 7)) << 3) | (lr & 7)] = f2bf(p);
        }
        for (int msk = 1; msk < 16; msk <<= 1) rs += __shfl_xor(rs, msk, 64);
        l_run[r] += rs;
      }
      // PV: acc += P(16x64) * V(64x64)  (Ps is wave-private: no barrier needed)
      __builtin_amdgcn_s_setprio(1);
      for (int kk = 0; kk < 2; kk++){
        bf16x8 pa = *(const bf16x8*)&Ps[w][lr][((kk * 4 + lg) ^ (lr & 7)) * 8];
        for (int df = 0; df < 4; df++){
          int row = df * 16 + lr;
          bf16x8 bv = *(const bf16x8*)&Vst[row][((kk * 4 + lg) ^ (lr & 7)) * 8];
          acc[df] = __builtin_amdgcn_mfma_f32_16x16x32_bf16(pa, bv, acc[df], 0, 0, 0);
        }
      }
      __builtin_amdgcn_s_setprio(0);
    }

    // write attn_vec (bf16)
    for (int df = 0; df < 4; df++){
      for (int r = 0; r < 4; r++){
        int i_glob = q0 + lg * 4 + r;
        AV[((size_t)i_glob * BATCH + b) * DMODEL + n * DHEAD + df * 16 + lr] =
            f2bf(acc[df][r] / l_run[r]);
      }
    }
    __syncthreads();
  }
}

// ---------------- LayerNorm: out = g*(xa+xb - mu)*rstd + b ----------------
__global__ __launch_bounds__(256) void ln_kernel(const float* __restrict__ xa,
                                                 const float* __restrict__ xb,
                                                 const float* __restrict__ gamma,
                                                 const float* __restrict__ beta,
                                                 float* __restrict__ outF,
                                                 short* __restrict__ outB){
  __shared__ float red[4];
  const int row = blockIdx.x, t = threadIdx.x;
  const size_t base = (size_t)row * DMODEL + t * 4;
  f32x4 a  = *(const f32x4*)(xa + base);
  f32x4 bb = *(const f32x4*)(xb + base);
  f32x4 x;
  for (int e = 0; e < 4; e++) x[e] = a[e] + bb[e];
  float sum = x[0] + x[1] + x[2] + x[3];
  for (int m = 1; m < 64; m <<= 1) sum += __shfl_xor(sum, m, 64);
  if ((t & 63) == 0) red[t >> 6] = sum;
  __syncthreads();
  float mu = (red[0] + red[1] + red[2] + red[3]) * (1.f / DMODEL);
  float sq = 0.f;
  for (int e = 0; e < 4; e++){ float d = x[e] - mu; sq += d * d; }
  for (int m = 1; m < 64; m <<= 1) sq += __shfl_xor(sq, m, 64);
  __syncthreads();
  if ((t & 63) == 0) red[t >> 6] = sq;
  __syncthreads();
  float var = (red[0] + red[1] + red[2] + red[3]) * (1.f / DMODEL);
  float rstd = rsqrtf(var + 1e-5f);
  f32x4 g  = *(const f32x4*)(gamma + t * 4);
  f32x4 be = *(const f32x4*)(beta + t * 4);
  for (int e = 0; e < 4; e++){
    float y = g[e] * (x[e] - mu) * rstd + be[e];
    if (outF) outF[base + e] = y;
    if (outB) outB[base + e] = f2bf(y);
  }
}

// ---------------- KL reduction ----------------
__global__ __launch_bounds__(256) void kl_kernel(const float* __restrict__ mean,
                                                 const float* __restrict__ stdv,
                                                 int n, double* acc){
  __shared__ double red[4];
  double local = 0.0;
  int stride = gridDim.x * 256;
  for (int i = blockIdx.x * 256 + threadIdx.x; i < n; i += stride){
    float m = mean[i], s = stdv[i];
    local += (double)(m * m) - 2.0 * (double)s + (double)expf(2.f * s);
  }
  for (int msk = 1; msk < 64; msk <<= 1) local += __shfl_xor(local, msk, 64);
  const int t = threadIdx.x;
  if ((t & 63) == 0) red[t >> 6] = local;
  __syncthreads();
  if (t == 0) atomicAdd(acc, red[0] + red[1] + red[2] + red[3]);
}

__global__ void kl_final(const double* acc, float* out){
  out[0] = (float)(acc[0] / 8388608.0 + acc[1] / 16777216.0);
}

// ---------------- launch ----------------
extern "C" void kernel_launch(void* const* d_in, const int* in_sizes, int n_in,
                              void* d_out, int out_size, void* d_ws, size_t ws_size,
                              hipStream_t stream){
  (void)in_sizes; (void)n_in; (void)out_size; (void)ws_size;
  const float* dec = (const float*)d_in[0];
  const float* qm  = (const float*)d_in[2];
  const float* km  = (const float*)d_in[3];
  const float* vm  = (const float*)d_in[4];
  const float* qs  = (const float*)d_in[5];
  const float* ks  = (const float*)d_in[6];
  const float* vs  = (const float*)d_in[7];
  const float* om  = (const float*)d_in[8];
  const float* os_ = (const float*)d_in[9];
  const float* g1  = (const float*)d_in[10];
  const float* b1  = (const float*)d_in[11];
  const float* w1m = (const float*)d_in[12];
  const float* w2m = (const float*)d_in[13];
  const float* w1s = (const float*)d_in[14];
  const float* w2s = (const float*)d_in[15];
  const float* g2  = (const float*)d_in[16];
  const float* b2  = (const float*)d_in[17];
  float* out = (float*)d_out;

  char* ws = (char*)d_ws;
  size_t off = 0;
  auto alloc = [&](size_t bytes) -> char* {
    char* p = ws + off;
    off += (bytes + 255) & ~(size_t)255;
    return p;
  };
  short* Xb   = (short*)alloc((size_t)MROWS * DMODEL * 2);   // X bf16; then h bf16
  short* Wqkv = (short*)alloc((size_t)QKVN * DMODEL * 2);    // [3072][1024]
  short* W1   = (short*)alloc((size_t)DFF * DMODEL * 2);
  short* W2   = (short*)alloc((size_t)DMODEL * DFF * 2);
  short* Wv   = Wqkv + (size_t)2 * DMODEL * DMODEL;          // V weights within Wqkv
  short* QKVb = (short*)alloc((size_t)MROWS * QKVN * 2);     // [4096][3072], 24MB
  short* AVb  = (short*)alloc((size_t)MROWS * DMODEL * 2);   // 8MB, contiguous after QKVb
  float* tmpF = (float*)alloc((size_t)MROWS * DMODEL * 4);
  float* hF   = (float*)alloc((size_t)MROWS * DMODEL * 4);
  double* acc = (double*)alloc(256);
  short* L1 = QKVb;  // reuse QKVb+AVb region (32MB) for l1 [4096][4096] bf16

  hipMemsetAsync(acc, 0, 16, stream);

  // casts
  cast_kernel<<<MROWS * DMODEL / 1024, 256, 0, stream>>>(dec, Xb, MROWS * DMODEL);
  cast_kernel<<<DMODEL * DMODEL / 1024, 256, 0, stream>>>(qm, Wqkv, DMODEL * DMODEL);
  cast_kernel<<<DMODEL * DMODEL / 1024, 256, 0, stream>>>(km, Wqkv + (size_t)DMODEL * DMODEL, DMODEL * DMODEL);
  cast_kernel<<<DMODEL * DMODEL / 1024, 256, 0, stream>>>(vm, Wqkv + (size_t)2 * DMODEL * DMODEL, DMODEL * DMODEL);
  cast_kernel<<<DFF * DMODEL / 1024, 256, 0, stream>>>(w1m, W1, DFF * DMODEL);
  cast_kernel<<<DMODEL * DFF / 1024, 256, 0, stream>>>(w2m, W2, DMODEL * DFF);

  // fused QKV projection: [4096][3072] = Xb[4096][1024] @ Wqkv^T
  gemm_bt<<<dim3(QKVN / 128, MROWS / 128), 512, 0, stream>>>(Xb, Wqkv, nullptr, QKVb, MROWS, QKVN, DMODEL);

  // attention
  attn_kernel<<<dim3(16, BATCH * NHEADS), 256, 0, stream>>>(QKVb, AVb);

  // attn output projection (bug-faithful: uses value_mean)
  gemm_bt<<<dim3(DMODEL / 128, MROWS / 128), 512, 0, stream>>>(AVb, Wv, tmpF, nullptr, MROWS, DMODEL, DMODEL);

  // LN1: h = LN(dec + attn_out) -> hF (f32) + Xb (bf16)
  ln_kernel<<<MROWS, 256, 0, stream>>>(dec, tmpF, g1, b1, hF, Xb);

  // FF
  gemm_bt<<<dim3(DFF / 128, MROWS / 128), 512, 0, stream>>>(Xb, W1, nullptr, L1, MROWS, DFF, DMODEL);
  gemm_bt<<<dim3(DMODEL / 128, MROWS / 128), 512, 0, stream>>>(L1, W2, tmpF, nullptr, MROWS, DMODEL, DFF);

  // LN2 -> final out
  ln_kernel<<<MROWS, 256, 0, stream>>>(hF, tmpF, g2, b2, out, nullptr);

  // KL
  kl_kernel<<<1024, 256, 0, stream>>>(qm, qs, DMODEL * DMODEL, acc);
  kl_kernel<<<1024, 256, 0, stream>>>(km, ks, DMODEL * DMODEL, acc);
  kl_kernel<<<1024, 256, 0, stream>>>(vm, vs, DMODEL * DMODEL, acc);
  kl_kernel<<<1024, 256, 0, stream>>>(om, os_, DMODEL * DMODEL, acc);
  kl_kernel<<<1024, 256, 0, stream>>>(w1m, w1s, DFF * DMODEL, acc + 1);
  kl_kernel<<<1024, 256, 0, stream>>>(w2m, w2s, DMODEL * DFF, acc + 1);
  kl_final<<<1, 1, 0, stream>>>(acc, out + (size_t)MROWS * DMODEL);
}

// Round 4
// 542.279 us; speedup vs baseline: 1.4068x; 1.0916x over previous
//
#include <hip/hip_runtime.h>

#define S_LEN  2048
#define BATCH  2
#define DMODEL 1024
#define NHEADS 16
#define DHEAD  64
#define DFF    4096
#define MROWS  (S_LEN*BATCH)   // 4096
#define QKVN   3072

typedef __attribute__((ext_vector_type(8))) short bf16x8;
typedef __attribute__((ext_vector_type(4))) float f32x4;
typedef __attribute__((ext_vector_type(4))) short s16x4;

#define NEG_BIG (-3.0e38f)
#define SCALE_LOG2 (0.125f * 1.4426950408889634f)

__device__ __forceinline__ short f2bf(float f){
  unsigned u = __float_as_uint(f);
  u += 0x7fffu + ((u >> 16) & 1u);
  return (short)(u >> 16);
}

__device__ __forceinline__ void gload16(const void* gptr, void* lptr){
  __builtin_amdgcn_global_load_lds(
      (const __attribute__((address_space(1))) unsigned int*)gptr,
      (__attribute__((address_space(3))) unsigned int*)lptr,
      16, 0, 0);
}

// ---------------- cast f32 -> bf16 ----------------
__global__ __launch_bounds__(256) void cast_kernel(const float* __restrict__ in,
                                                   short* __restrict__ out, int n){
  int i = (blockIdx.x * 256 + threadIdx.x) * 4;
  if (i >= n) return;
  f32x4 v = *(const f32x4*)(in + i);
  s16x4 o;
  o[0] = f2bf(v[0]); o[1] = f2bf(v[1]); o[2] = f2bf(v[2]); o[3] = f2bf(v[3]);
  *(s16x4*)(out + i) = o;
}

// ---------------- GEMM: C[M][N] = A[M][K] * Bt[N][K]^T ----------------
// m97 structure: 128xBN tile, BK=32, 8 waves (512 thr), global_load_lds w=16
// BN=128 for wide-N GEMMs; BN=64 doubles grid parallelism for N=1024 GEMMs.
template<int BN>
__global__ __launch_bounds__(512) void gemm_bt(const short* __restrict__ A,
                                               const short* __restrict__ Bt,
                                               float* __restrict__ Cf,
                                               short* __restrict__ Cb,
                                               int M, int N, int K){
  __shared__ short As[128][32];
  __shared__ short Bs[BN][32];
  constexpr int NB = BN / 32;   // n-frags per wave
  const int t = threadIdx.x;
  const int lane = t & 63, w = t >> 6;
  const int m0 = blockIdx.y * 128, n0 = blockIdx.x * BN;
  const int wm = (w & 3) * 32, wn = (w >> 2) * (BN / 2);
  const int lr = lane & 15, lg = lane >> 4;

  f32x4 acc[2][NB] = {};

  const short* Ap = A  + (size_t)(m0 + (t >> 2)) * K + (t & 3) * 8;
  const short* Bp = Bt + (size_t)(n0 + ((t & (BN * 4 - 1)) >> 2)) * K + (t & 3) * 8;
  char* ldsA = (char*)(&As[0][0]) + w * 1024;
  char* ldsB = (char*)(&Bs[0][0]) + (w & (BN / 32 * 2 - 1)) * 1024;

  for (int k0 = 0; k0 < K; k0 += 32){
    gload16(Ap + k0, ldsA);
    if (BN == 128 || t < 256) gload16(Bp + k0, ldsB);
    __syncthreads();
    bf16x8 a0 = *(const bf16x8*)&As[wm      + lr][lg * 8];
    bf16x8 a1 = *(const bf16x8*)&As[wm + 16 + lr][lg * 8];
    bf16x8 bfr[NB];
    for (int ni = 0; ni < NB; ni++)
      bfr[ni] = *(const bf16x8*)&Bs[wn + ni * 16 + lr][lg * 8];
    for (int ni = 0; ni < NB; ni++){
      acc[0][ni] = __builtin_amdgcn_mfma_f32_16x16x32_bf16(a0, bfr[ni], acc[0][ni], 0, 0, 0);
      acc[1][ni] = __builtin_amdgcn_mfma_f32_16x16x32_bf16(a1, bfr[ni], acc[1][ni], 0, 0, 0);
    }
    __syncthreads();
  }

  for (int mi = 0; mi < 2; mi++){
    for (int ni = 0; ni < NB; ni++){
      int row = m0 + wm + mi * 16 + lg * 4;
      int col = n0 + wn + ni * 16 + lr;
      for (int r = 0; r < 4; r++){
        float v = acc[mi][ni][r];
        if (Cf) Cf[(size_t)(row + r) * N + col] = v;
        if (Cb) Cb[(size_t)(row + r) * N + col] = f2bf(v);
      }
    }
  }
}

// ---------------- fused causal flash attention (swapped-QK^T) ----------------
// grid (16, B*NH): each block does q-tiles bx and 31-bx (uniform 33 K-tiles)
// block 256 (4 waves x 16 q-rows). mfma(K,Q) => S[j][q=lr]: softmax is
// thread-local per q-row; P packs to b64 LDS writes (XOR-swizzled Pt).
__global__ __launch_bounds__(256) void attn_kernel(const short* __restrict__ QKV,
                                                   short* __restrict__ AV){
  __shared__ short Ks[64][64];
  __shared__ short Vst[64][64];   // transposed: [dh][j], swizzled
  __shared__ short Pt[4][16][64]; // per-wave P^T: [q(lr)][j], swizzled
  const int t = threadIdx.x, lane = t & 63, w = t >> 6;
  const int hb = blockIdx.y;
  const int b = hb >> 4, n = hb & 15;
  const int lr = lane & 15, lg = lane >> 4;

  for (int half = 0; half < 2; half++){
    const int qt = half ? (31 - (int)blockIdx.x) : (int)blockIdx.x;
    const int q0w = qt * 64 + w * 16;

    // Q fragments: b-operand rows q = q0w + lr, k = kk*32 + lg*8 + i
    bf16x8 aq[2];
    {
      const short* qp = QKV + ((size_t)(q0w + lr) * BATCH + b) * QKVN + n * DHEAD + lg * 8;
      aq[0] = *(const bf16x8*)(qp);
      aq[1] = *(const bf16x8*)(qp + 32);
    }

    f32x4 acc[4] = {};
    float m_run = NEG_BIG, l_run = 0.f;

    for (int jt = 0; jt <= qt; jt++){
      const int j0 = jt * 64;
      __syncthreads();
      {
        // stage K tile [64 j][64 d], swizzled units
        int j = t >> 2, u0 = (t & 3) * 2;
        const short* kp = QKV + ((size_t)(j0 + j) * BATCH + b) * QKVN + DMODEL + n * DHEAD + u0 * 8;
        *(bf16x8*)&Ks[j][(u0 ^ (j & 7)) * 8]       = *(const bf16x8*)(kp);
        *(bf16x8*)&Ks[j][((u0 + 1) ^ (j & 7)) * 8] = *(const bf16x8*)(kp + 8);
        // stage V transposed [64 dh][64 j], swizzled
        int jv = t & 63, dq = (t >> 6) * 16;
        const short* vp = QKV + ((size_t)(j0 + jv) * BATCH + b) * QKVN + 2 * DMODEL + n * DHEAD + dq;
        bf16x8 v0 = *(const bf16x8*)(vp);
        bf16x8 v1 = *(const bf16x8*)(vp + 8);
        int uj = jv >> 3, jl = jv & 7;
        for (int e = 0; e < 8; e++){
          int sc = (((uj ^ e) << 3) | jl);
          Vst[dq + e][sc]     = v0[e];
          Vst[dq + 8 + e][sc] = v1[e];
        }
      }
      __syncthreads();

      // scores (swapped): s[nf] = S[j = j0 + nf*16 + lg*4 + r][q = q0w + lr]
      f32x4 s[4];
      __builtin_amdgcn_s_setprio(1);
      for (int nf = 0; nf < 4; nf++){
        f32x4 z = {};
        for (int kk = 0; kk < 2; kk++){
          bf16x8 bk = *(const bf16x8*)&Ks[nf * 16 + lr][((kk * 4 + lg) ^ (lr & 7)) * 8];
          z = __builtin_amdgcn_mfma_f32_16x16x32_bf16(bk, aq[kk], z, 0, 0, 0);
        }
        s[nf] = z;
      }
      __builtin_amdgcn_s_setprio(0);

      for (int nf = 0; nf < 4; nf++)
        for (int r = 0; r < 4; r++) s[nf][r] *= SCALE_LOG2;

      if (jt == qt){   // wave-uniform: mask only the diagonal tile
        int qg = q0w + lr;
        for (int nf = 0; nf < 4; nf++)
          for (int r = 0; r < 4; r++)
            if (j0 + nf * 16 + lg * 4 + r > qg) s[nf][r] = NEG_BIG;
      }

      // row max over 16 local + 2 shfl (reduce across lg)
      float mx = NEG_BIG;
      for (int nf = 0; nf < 4; nf++){
        float a0 = fmaxf(s[nf][0], s[nf][1]);
        float a1 = fmaxf(s[nf][2], s[nf][3]);
        mx = fmaxf(mx, fmaxf(a0, a1));
      }
      mx = fmaxf(mx, __shfl_xor(mx, 16, 64));
      mx = fmaxf(mx, __shfl_xor(mx, 32, 64));
      float mn = fmaxf(m_run, mx);
      float corr = __builtin_exp2f(m_run - mn);
      m_run = mn;

      // P = exp2(S - m) + row sum
      float rs = 0.f;
      for (int nf = 0; nf < 4; nf++)
        for (int r = 0; r < 4; r++){
          float p = __builtin_exp2f(s[nf][r] - mn);
          s[nf][r] = p;
          rs += p;
        }
      rs += __shfl_xor(rs, 16, 64);
      rs += __shfl_xor(rs, 32, 64);
      l_run = l_run * corr + rs;

      // pack P (truncate to bf16) -> swizzled Pt row q=lr, b64 writes
      char* prow = (char*)&Pt[w][lr][0];
      for (int nf = 0; nf < 4; nf++){
        unsigned u0 = __float_as_uint(s[nf][0]);
        unsigned u1 = __float_as_uint(s[nf][1]);
        unsigned u2 = __float_as_uint(s[nf][2]);
        unsigned u3 = __float_as_uint(s[nf][3]);
        uint2 val;
        val.x = (u0 >> 16) | (u1 & 0xffff0000u);
        val.y = (u2 >> 16) | (u3 & 0xffff0000u);
        int off = ((((nf * 2) + (lg >> 1)) ^ (lr & 7)) << 4) + ((lg & 1) << 3);
        *(uint2*)(prow + off) = val;
      }

      // rescale acc (corr broadcast to acc-row owners)
      float cb[4];
      for (int r = 0; r < 4; r++) cb[r] = __shfl(corr, lg * 4 + r, 64);
      for (int df = 0; df < 4; df++)
        for (int r = 0; r < 4; r++) acc[df][r] *= cb[r];

      // PV: acc[df] += P(16q x 64j) * V(64j x 16dh)
      __builtin_amdgcn_s_setprio(1);
      for (int kk = 0; kk < 2; kk++){
        bf16x8 pa = *(const bf16x8*)(prow + ((((kk * 4) + lg) ^ (lr & 7)) << 4));
        for (int df = 0; df < 4; df++){
          bf16x8 bv = *(const bf16x8*)&Vst[df * 16 + lr][((kk * 4 + lg) ^ (lr & 7)) * 8];
          acc[df] = __builtin_amdgcn_mfma_f32_16x16x32_bf16(pa, bv, acc[df], 0, 0, 0);
        }
      }
      __builtin_amdgcn_s_setprio(0);
    }

    // epilogue: divide by l (broadcast to acc-row owners), write attn_vec
    float lb[4];
    for (int r = 0; r < 4; r++) lb[r] = __shfl(l_run, lg * 4 + r, 64);
    for (int df = 0; df < 4; df++){
      for (int r = 0; r < 4; r++){
        int i_glob = q0w + lg * 4 + r;
        AV[((size_t)i_glob * BATCH + b) * DMODEL + n * DHEAD + df * 16 + lr] =
            f2bf(acc[df][r] / lb[r]);
      }
    }
    __syncthreads();
  }
}

// ---------------- LayerNorm: out = g*(xa+xb - mu)*rstd + b ----------------
__global__ __launch_bounds__(256) void ln_kernel(const float* __restrict__ xa,
                                                 const float* __restrict__ xb,
                                                 const float* __restrict__ gamma,
                                                 const float* __restrict__ beta,
                                                 float* __restrict__ outF,
                                                 short* __restrict__ outB){
  __shared__ float red[4];
  const int row = blockIdx.x, t = threadIdx.x;
  const size_t base = (size_t)row * DMODEL + t * 4;
  f32x4 a  = *(const f32x4*)(xa + base);
  f32x4 bb = *(const f32x4*)(xb + base);
  f32x4 x;
  for (int e = 0; e < 4; e++) x[e] = a[e] + bb[e];
  float sum = x[0] + x[1] + x[2] + x[3];
  for (int m = 1; m < 64; m <<= 1) sum += __shfl_xor(sum, m, 64);
  if ((t & 63) == 0) red[t >> 6] = sum;
  __syncthreads();
  float mu = (red[0] + red[1] + red[2] + red[3]) * (1.f / DMODEL);
  float sq = 0.f;
  for (int e = 0; e < 4; e++){ float d = x[e] - mu; sq += d * d; }
  for (int m = 1; m < 64; m <<= 1) sq += __shfl_xor(sq, m, 64);
  __syncthreads();
  if ((t & 63) == 0) red[t >> 6] = sq;
  __syncthreads();
  float var = (red[0] + red[1] + red[2] + red[3]) * (1.f / DMODEL);
  float rstd = rsqrtf(var + 1e-5f);
  f32x4 g  = *(const f32x4*)(gamma + t * 4);
  f32x4 be = *(const f32x4*)(beta + t * 4);
  for (int e = 0; e < 4; e++){
    float y = g[e] * (x[e] - mu) * rstd + be[e];
    if (outF) outF[base + e] = y;
    if (outB) outB[base + e] = f2bf(y);
  }
}

// ---------------- KL reduction ----------------
__global__ __launch_bounds__(256) void kl_kernel(const float* __restrict__ mean,
                                                 const float* __restrict__ stdv,
                                                 int n, double* acc){
  __shared__ double red[4];
  double local = 0.0;
  int stride = gridDim.x * 256;
  for (int i = blockIdx.x * 256 + threadIdx.x; i < n; i += stride){
    float m = mean[i], s = stdv[i];
    local += (double)(m * m) - 2.0 * (double)s + (double)expf(2.f * s);
  }
  for (int msk = 1; msk < 64; msk <<= 1) local += __shfl_xor(local, msk, 64);
  const int t = threadIdx.x;
  if ((t & 63) == 0) red[t >> 6] = local;
  __syncthreads();
  if (t == 0) atomicAdd(acc, red[0] + red[1] + red[2] + red[3]);
}

__global__ void kl_final(const double* acc, float* out){
  out[0] = (float)(acc[0] / 8388608.0 + acc[1] / 16777216.0);
}

// ---------------- launch ----------------
extern "C" void kernel_launch(void* const* d_in, const int* in_sizes, int n_in,
                              void* d_out, int out_size, void* d_ws, size_t ws_size,
                              hipStream_t stream){
  (void)in_sizes; (void)n_in; (void)out_size; (void)ws_size;
  const float* dec = (const float*)d_in[0];
  const float* qm  = (const float*)d_in[2];
  const float* km  = (const float*)d_in[3];
  const float* vm  = (const float*)d_in[4];
  const float* qs  = (const float*)d_in[5];
  const float* ks  = (const float*)d_in[6];
  const float* vs  = (const float*)d_in[7];
  const float* om  = (const float*)d_in[8];
  const float* os_ = (const float*)d_in[9];
  const float* g1  = (const float*)d_in[10];
  const float* b1  = (const float*)d_in[11];
  const float* w1m = (const float*)d_in[12];
  const float* w2m = (const float*)d_in[13];
  const float* w1s = (const float*)d_in[14];
  const float* w2s = (const float*)d_in[15];
  const float* g2  = (const float*)d_in[16];
  const float* b2  = (const float*)d_in[17];
  float* out = (float*)d_out;

  char* ws = (char*)d_ws;
  size_t off = 0;
  auto alloc = [&](size_t bytes) -> char* {
    char* p = ws + off;
    off += (bytes + 255) & ~(size_t)255;
    return p;
  };
  short* Xb   = (short*)alloc((size_t)MROWS * DMODEL * 2);   // X bf16; then h bf16
  short* Wqkv = (short*)alloc((size_t)QKVN * DMODEL * 2);    // [3072][1024]
  short* W1   = (short*)alloc((size_t)DFF * DMODEL * 2);
  short* W2   = (short*)alloc((size_t)DMODEL * DFF * 2);
  short* Wv   = Wqkv + (size_t)2 * DMODEL * DMODEL;          // V weights within Wqkv
  short* QKVb = (short*)alloc((size_t)MROWS * QKVN * 2);     // [4096][3072], 24MB
  short* AVb  = (short*)alloc((size_t)MROWS * DMODEL * 2);   // 8MB, contiguous after QKVb
  float* tmpF = (float*)alloc((size_t)MROWS * DMODEL * 4);
  float* hF   = (float*)alloc((size_t)MROWS * DMODEL * 4);
  double* acc = (double*)alloc(256);
  short* L1 = QKVb;  // reuse QKVb+AVb region (32MB) for l1 [4096][4096] bf16

  hipMemsetAsync(acc, 0, 16, stream);

  // casts
  cast_kernel<<<MROWS * DMODEL / 1024, 256, 0, stream>>>(dec, Xb, MROWS * DMODEL);
  cast_kernel<<<DMODEL * DMODEL / 1024, 256, 0, stream>>>(qm, Wqkv, DMODEL * DMODEL);
  cast_kernel<<<DMODEL * DMODEL / 1024, 256, 0, stream>>>(km, Wqkv + (size_t)DMODEL * DMODEL, DMODEL * DMODEL);
  cast_kernel<<<DMODEL * DMODEL / 1024, 256, 0, stream>>>(vm, Wqkv + (size_t)2 * DMODEL * DMODEL, DMODEL * DMODEL);
  cast_kernel<<<DFF * DMODEL / 1024, 256, 0, stream>>>(w1m, W1, DFF * DMODEL);
  cast_kernel<<<DMODEL * DFF / 1024, 256, 0, stream>>>(w2m, W2, DMODEL * DFF);

  // fused QKV projection: [4096][3072] = Xb[4096][1024] @ Wqkv^T
  gemm_bt<128><<<dim3(QKVN / 128, MROWS / 128), 512, 0, stream>>>(Xb, Wqkv, nullptr, QKVb, MROWS, QKVN, DMODEL);

  // attention
  attn_kernel<<<dim3(16, BATCH * NHEADS), 256, 0, stream>>>(QKVb, AVb);

  // attn output projection (bug-faithful: uses value_mean); BN=64 -> 512 blocks
  gemm_bt<64><<<dim3(DMODEL / 64, MROWS / 128), 512, 0, stream>>>(AVb, Wv, tmpF, nullptr, MROWS, DMODEL, DMODEL);

  // LN1: h = LN(dec + attn_out) -> hF (f32) + Xb (bf16)
  ln_kernel<<<MROWS, 256, 0, stream>>>(dec, tmpF, g1, b1, hF, Xb);

  // FF
  gemm_bt<128><<<dim3(DFF / 128, MROWS / 128), 512, 0, stream>>>(Xb, W1, nullptr, L1, MROWS, DFF, DMODEL);
  gemm_bt<64><<<dim3(DMODEL / 64, MROWS / 128), 512, 0, stream>>>(L1, W2, tmpF, nullptr, MROWS, DMODEL, DFF);

  // LN2 -> final out
  ln_kernel<<<MROWS, 256, 0, stream>>>(hF, tmpF, g2, b2, out, nullptr);

  // KL
  kl_kernel<<<1024, 256, 0, stream>>>(qm, qs, DMODEL * DMODEL, acc);
  kl_kernel<<<1024, 256, 0, stream>>>(km, ks, DMODEL * DMODEL, acc);
  kl_kernel<<<1024, 256, 0, stream>>>(vm, vs, DMODEL * DMODEL, acc);
  kl_kernel<<<1024, 256, 0, stream>>>(om, os_, DMODEL * DMODEL, acc);
  kl_kernel<<<1024, 256, 0, stream>>>(w1m, w1s, DFF * DMODEL, acc + 1);
  kl_kernel<<<1024, 256, 0, stream>>>(w2m, w2s, DMODEL * DFF, acc + 1);
  kl_final<<<1, 1, 0, stream>>>(acc, out + (size_t)MROWS * DMODEL);
}

// Round 6
// 523.396 us; speedup vs baseline: 1.4576x; 1.0361x over previous
//
#include <hip/hip_runtime.h>

#define S_LEN  2048
#define BATCH  2
#define DMODEL 1024
#define NHEADS 16
#define DHEAD  64
#define DFF    4096
#define MROWS  (S_LEN*BATCH)   // 4096
#define QKVN   3072

typedef __attribute__((ext_vector_type(8))) short bf16x8;
typedef __attribute__((ext_vector_type(4))) float f32x4;
typedef __attribute__((ext_vector_type(4))) short s16x4;

#define NEG_BIG (-3.0e38f)
#define SCALE_LOG2 (0.125f * 1.4426950408889634f)

__device__ __forceinline__ short f2bf(float f){
  unsigned u = __float_as_uint(f);
  u += 0x7fffu + ((u >> 16) & 1u);
  return (short)(u >> 16);
}

__device__ __forceinline__ void gload16(const void* gptr, void* lptr){
  __builtin_amdgcn_global_load_lds(
      (const __attribute__((address_space(1))) unsigned int*)gptr,
      (__attribute__((address_space(3))) unsigned int*)lptr,
      16, 0, 0);
}

// ---------------- cast f32 -> bf16 ----------------
__global__ __launch_bounds__(256) void cast_kernel(const float* __restrict__ in,
                                                   short* __restrict__ out, int n){
  int i = (blockIdx.x * 256 + threadIdx.x) * 4;
  if (i >= n) return;
  f32x4 v = *(const f32x4*)(in + i);
  s16x4 o;
  o[0] = f2bf(v[0]); o[1] = f2bf(v[1]); o[2] = f2bf(v[2]); o[3] = f2bf(v[3]);
  *(s16x4*)(out + i) = o;
}

// ---------------- fused cast + KL: out=bf16(mean); acc += KL(mean,std) ------
__global__ __launch_bounds__(256) void cast_kl_kernel(const float* __restrict__ mean,
                                                      const float* __restrict__ stdv,
                                                      short* __restrict__ outb,
                                                      int n, double* acc){
  __shared__ double red[4];
  double local = 0.0;
  const int stride = gridDim.x * 1024;
  for (int i = (blockIdx.x * 256 + threadIdx.x) * 4; i < n; i += stride){
    f32x4 m = *(const f32x4*)(mean + i);
    f32x4 sv = *(const f32x4*)(stdv + i);
    if (outb){
      s16x4 o;
      o[0] = f2bf(m[0]); o[1] = f2bf(m[1]); o[2] = f2bf(m[2]); o[3] = f2bf(m[3]);
      *(s16x4*)(outb + i) = o;
    }
    for (int e = 0; e < 4; e++)
      local += (double)(m[e] * m[e]) - 2.0 * (double)sv[e] + (double)expf(2.f * sv[e]);
  }
  for (int msk = 1; msk < 64; msk <<= 1) local += __shfl_xor(local, msk, 64);
  const int t = threadIdx.x;
  if ((t & 63) == 0) red[t >> 6] = local;
  __syncthreads();
  if (t == 0) atomicAdd(acc, red[0] + red[1] + red[2] + red[3]);
}

__global__ void kl_final(const double* acc, float* out){
  out[0] = (float)(acc[0] / 8388608.0 + acc[1] / 16777216.0);
}

// ---------------- GEMM: C[M][N] = A[M][K] * Bt[N][K]^T ----------------
// 128xBN tile, BK=32, 8 waves, global_load_lds w=16, double-buffered LDS,
// 2-phase pipeline: stage(next) -> MFMA(cur) -> vmcnt(0)+s_barrier.
// 1D grid with chunked XCD swizzle (nwg % 8 == 0 required).
template<int BN>
__global__ __launch_bounds__(512) void gemm_bt(const short* __restrict__ A,
                                               const short* __restrict__ Bt,
                                               float* __restrict__ Cf,
                                               short* __restrict__ Cb,
                                               int M, int N, int K, int nbx){
  __shared__ short As[2][128][32];
  __shared__ short Bs[2][BN][32];
  constexpr int NB = BN / 32;   // n-frags per wave
  const int t = threadIdx.x;
  const int lane = t & 63, w = t >> 6;
  // chunked XCD swizzle: consecutive swizzled ids share the A-panel (same by)
  const int q8 = (int)gridDim.x >> 3;
  const int sid = ((int)blockIdx.x & 7) * q8 + ((int)blockIdx.x >> 3);
  const int bx = sid % nbx, by = sid / nbx;
  const int m0 = by * 128, n0 = bx * BN;
  const int wm = (w & 3) * 32, wn = (w >> 2) * (BN / 2);
  const int lr = lane & 15, lg = lane >> 4;

  f32x4 acc[2][NB] = {};

  const short* Ap = A  + (size_t)(m0 + (t >> 2)) * K + (t & 3) * 8;
  const short* Bp = Bt + (size_t)(n0 + ((t & (BN * 4 - 1)) >> 2)) * K + (t & 3) * 8;
  char* ldsA0 = (char*)As + w * 1024;
  char* ldsB0 = (char*)Bs + (w & (NB * 2 - 1)) * 1024;
  constexpr int BSTRIDE = BN * 64;  // bytes per B buffer

  // prologue: stage tile 0 into buf 0
  gload16(Ap, ldsA0);
  if (BN == 128 || t < 256) gload16(Bp, ldsB0);
  asm volatile("s_waitcnt vmcnt(0)" ::: "memory");
  __builtin_amdgcn_s_barrier();
  asm volatile("" ::: "memory");

  int cur = 0;
  for (int k0 = 0; k0 < K; k0 += 32){
    if (k0 + 32 < K){
      gload16(Ap + k0 + 32, ldsA0 + (cur ^ 1) * 8192);
      if (BN == 128 || t < 256) gload16(Bp + k0 + 32, ldsB0 + (cur ^ 1) * BSTRIDE);
    }
    bf16x8 a0 = *(const bf16x8*)&As[cur][wm      + lr][lg * 8];
    bf16x8 a1 = *(const bf16x8*)&As[cur][wm + 16 + lr][lg * 8];
    bf16x8 bfr[NB];
    for (int ni = 0; ni < NB; ni++)
      bfr[ni] = *(const bf16x8*)&Bs[cur][wn + ni * 16 + lr][lg * 8];
    for (int ni = 0; ni < NB; ni++){
      acc[0][ni] = __builtin_amdgcn_mfma_f32_16x16x32_bf16(a0, bfr[ni], acc[0][ni], 0, 0, 0);
      acc[1][ni] = __builtin_amdgcn_mfma_f32_16x16x32_bf16(a1, bfr[ni], acc[1][ni], 0, 0, 0);
    }
    asm volatile("s_waitcnt vmcnt(0)" ::: "memory");
    __builtin_amdgcn_s_barrier();
    asm volatile("" ::: "memory");
    cur ^= 1;
  }

  for (int mi = 0; mi < 2; mi++){
    for (int ni = 0; ni < NB; ni++){
      int row = m0 + wm + mi * 16 + lg * 4;
      int col = n0 + wn + ni * 16 + lr;
      for (int r = 0; r < 4; r++){
        float v = acc[mi][ni][r];
        if (Cf) Cf[(size_t)(row + r) * N + col] = v;
        if (Cb) Cb[(size_t)(row + r) * N + col] = f2bf(v);
      }
    }
  }
}

// ---------------- fused causal flash attention (swapped-QK^T) ----------------
// grid (16, B*NH): each block does q-tiles bx and 31-bx (uniform 33 K-tiles)
// block 256 (4 waves x 16 q-rows). mfma(K,Q) => S[j][q=lr]: softmax is
// thread-local per q-row; P packs to b64 LDS writes (XOR-swizzled Pt).
__global__ __launch_bounds__(256) void attn_kernel(const short* __restrict__ QKV,
                                                   short* __restrict__ AV){
  __shared__ short Ks[64][64];
  __shared__ short Vst[64][64];   // transposed: [dh][j], swizzled
  __shared__ short Pt[4][16][64]; // per-wave P^T: [q(lr)][j], swizzled
  const int t = threadIdx.x, lane = t & 63, w = t >> 6;
  const int hb = blockIdx.y;
  const int b = hb >> 4, n = hb & 15;
  const int lr = lane & 15, lg = lane >> 4;

  for (int half = 0; half < 2; half++){
    const int qt = half ? (31 - (int)blockIdx.x) : (int)blockIdx.x;
    const int q0w = qt * 64 + w * 16;

    // Q fragments: b-operand rows q = q0w + lr, k = kk*32 + lg*8 + i
    bf16x8 aq[2];
    {
      const short* qp = QKV + ((size_t)(q0w + lr) * BATCH + b) * QKVN + n * DHEAD + lg * 8;
      aq[0] = *(const bf16x8*)(qp);
      aq[1] = *(const bf16x8*)(qp + 32);
    }

    f32x4 acc[4] = {};
    float m_run = NEG_BIG, l_run = 0.f;

    for (int jt = 0; jt <= qt; jt++){
      const int j0 = jt * 64;
      __syncthreads();
      {
        // stage K tile [64 j][64 d], swizzled units
        int j = t >> 2, u0 = (t & 3) * 2;
        const short* kp = QKV + ((size_t)(j0 + j) * BATCH + b) * QKVN + DMODEL + n * DHEAD + u0 * 8;
        *(bf16x8*)&Ks[j][(u0 ^ (j & 7)) * 8]       = *(const bf16x8*)(kp);
        *(bf16x8*)&Ks[j][((u0 + 1) ^ (j & 7)) * 8] = *(const bf16x8*)(kp + 8);
        // stage V transposed [64 dh][64 j], swizzled
        int jv = t & 63, dq = (t >> 6) * 16;
        const short* vp = QKV + ((size_t)(j0 + jv) * BATCH + b) * QKVN + 2 * DMODEL + n * DHEAD + dq;
        bf16x8 v0 = *(const bf16x8*)(vp);
        bf16x8 v1 = *(const bf16x8*)(vp + 8);
        int uj = jv >> 3, jl = jv & 7;
        for (int e = 0; e < 8; e++){
          int sc = (((uj ^ e) << 3) | jl);
          Vst[dq + e][sc]     = v0[e];
          Vst[dq + 8 + e][sc] = v1[e];
        }
      }
      __syncthreads();

      // scores (swapped): s[nf] = S[j = j0 + nf*16 + lg*4 + r][q = q0w + lr]
      f32x4 s[4];
      __builtin_amdgcn_s_setprio(1);
      for (int nf = 0; nf < 4; nf++){
        f32x4 z = {};
        for (int kk = 0; kk < 2; kk++){
          bf16x8 bk = *(const bf16x8*)&Ks[nf * 16 + lr][((kk * 4 + lg) ^ (lr & 7)) * 8];
          z = __builtin_amdgcn_mfma_f32_16x16x32_bf16(bk, aq[kk], z, 0, 0, 0);
        }
        s[nf] = z;
      }
      __builtin_amdgcn_s_setprio(0);

      for (int nf = 0; nf < 4; nf++)
        for (int r = 0; r < 4; r++) s[nf][r] *= SCALE_LOG2;

      if (jt == qt){   // wave-uniform: mask only the diagonal tile
        int qg = q0w + lr;
        for (int nf = 0; nf < 4; nf++)
          for (int r = 0; r < 4; r++)
            if (j0 + nf * 16 + lg * 4 + r > qg) s[nf][r] = NEG_BIG;
      }

      // row max over 16 local + 2 shfl (reduce across lg)
      float mx = NEG_BIG;
      for (int nf = 0; nf < 4; nf++){
        float a0 = fmaxf(s[nf][0], s[nf][1]);
        float a1 = fmaxf(s[nf][2], s[nf][3]);
        mx = fmaxf(mx, fmaxf(a0, a1));
      }
      mx = fmaxf(mx, __shfl_xor(mx, 16, 64));
      mx = fmaxf(mx, __shfl_xor(mx, 32, 64));
      float mn = fmaxf(m_run, mx);
      float corr = __builtin_exp2f(m_run - mn);
      m_run = mn;

      // P = exp2(S - m) + row sum
      float rs = 0.f;
      for (int nf = 0; nf < 4; nf++)
        for (int r = 0; r < 4; r++){
          float p = __builtin_exp2f(s[nf][r] - mn);
          s[nf][r] = p;
          rs += p;
        }
      rs += __shfl_xor(rs, 16, 64);
      rs += __shfl_xor(rs, 32, 64);
      l_run = l_run * corr + rs;

      // pack P (truncate to bf16) -> swizzled Pt row q=lr, b64 writes
      char* prow = (char*)&Pt[w][lr][0];
      for (int nf = 0; nf < 4; nf++){
        unsigned u0 = __float_as_uint(s[nf][0]);
        unsigned u1 = __float_as_uint(s[nf][1]);
        unsigned u2 = __float_as_uint(s[nf][2]);
        unsigned u3 = __float_as_uint(s[nf][3]);
        uint2 val;
        val.x = (u0 >> 16) | (u1 & 0xffff0000u);
        val.y = (u2 >> 16) | (u3 & 0xffff0000u);
        int off = ((((nf * 2) + (lg >> 1)) ^ (lr & 7)) << 4) + ((lg & 1) << 3);
        *(uint2*)(prow + off) = val;
      }

      // rescale acc (corr broadcast to acc-row owners)
      float cb[4];
      for (int r = 0; r < 4; r++) cb[r] = __shfl(corr, lg * 4 + r, 64);
      for (int df = 0; df < 4; df++)
        for (int r = 0; r < 4; r++) acc[df][r] *= cb[r];

      // PV: acc[df] += P(16q x 64j) * V(64j x 16dh)
      __builtin_amdgcn_s_setprio(1);
      for (int kk = 0; kk < 2; kk++){
        bf16x8 pa = *(const bf16x8*)(prow + ((((kk * 4) + lg) ^ (lr & 7)) << 4));
        for (int df = 0; df < 4; df++){
          bf16x8 bv = *(const bf16x8*)&Vst[df * 16 + lr][((kk * 4 + lg) ^ (lr & 7)) * 8];
          acc[df] = __builtin_amdgcn_mfma_f32_16x16x32_bf16(pa, bv, acc[df], 0, 0, 0);
        }
      }
      __builtin_amdgcn_s_setprio(0);
    }

    // epilogue: divide by l (broadcast to acc-row owners), write attn_vec
    float lb[4];
    for (int r = 0; r < 4; r++) lb[r] = __shfl(l_run, lg * 4 + r, 64);
    for (int df = 0; df < 4; df++){
      for (int r = 0; r < 4; r++){
        int i_glob = q0w + lg * 4 + r;
        AV[((size_t)i_glob * BATCH + b) * DMODEL + n * DHEAD + df * 16 + lr] =
            f2bf(acc[df][r] / lb[r]);
      }
    }
    __syncthreads();
  }
}

// ---------------- LayerNorm: out = g*(xa+xb - mu)*rstd + b ----------------
__global__ __launch_bounds__(256) void ln_kernel(const float* __restrict__ xa,
                                                 const float* __restrict__ xb,
                                                 const float* __restrict__ gamma,
                                                 const float* __restrict__ beta,
                                                 float* __restrict__ outF,
                                                 short* __restrict__ outB){
  __shared__ float red[4];
  const int row = blockIdx.x, t = threadIdx.x;
  const size_t base = (size_t)row * DMODEL + t * 4;
  f32x4 a  = *(const f32x4*)(xa + base);
  f32x4 bb = *(const f32x4*)(xb + base);
  f32x4 x;
  for (int e = 0; e < 4; e++) x[e] = a[e] + bb[e];
  float sum = x[0] + x[1] + x[2] + x[3];
  for (int m = 1; m < 64; m <<= 1) sum += __shfl_xor(sum, m, 64);
  if ((t & 63) == 0) red[t >> 6] = sum;
  __syncthreads();
  float mu = (red[0] + red[1] + red[2] + red[3]) * (1.f / DMODEL);
  float sq = 0.f;
  for (int e = 0; e < 4; e++){ float d = x[e] - mu; sq += d * d; }
  for (int m = 1; m < 64; m <<= 1) sq += __shfl_xor(sq, m, 64);
  __syncthreads();
  if ((t & 63) == 0) red[t >> 6] = sq;
  __syncthreads();
  float var = (red[0] + red[1] + red[2] + red[3]) * (1.f / DMODEL);
  float rstd = rsqrtf(var + 1e-5f);
  f32x4 g  = *(const f32x4*)(gamma + t * 4);
  f32x4 be = *(const f32x4*)(beta + t * 4);
  for (int e = 0; e < 4; e++){
    float y = g[e] * (x[e] - mu) * rstd + be[e];
    if (outF) outF[base + e] = y;
    if (outB) outB[base + e] = f2bf(y);
  }
}

// ---------------- launch ----------------
extern "C" void kernel_launch(void* const* d_in, const int* in_sizes, int n_in,
                              void* d_out, int out_size, void* d_ws, size_t ws_size,
                              hipStream_t stream){
  (void)in_sizes; (void)n_in; (void)out_size; (void)ws_size;
  const float* dec = (const float*)d_in[0];
  const float* qm  = (const float*)d_in[2];
  const float* km  = (const float*)d_in[3];
  const float* vm  = (const float*)d_in[4];
  const float* qs  = (const float*)d_in[5];
  const float* ks  = (const float*)d_in[6];
  const float* vs  = (const float*)d_in[7];
  const float* om  = (const float*)d_in[8];
  const float* os_ = (const float*)d_in[9];
  const float* g1  = (const float*)d_in[10];
  const float* b1  = (const float*)d_in[11];
  const float* w1m = (const float*)d_in[12];
  const float* w2m = (const float*)d_in[13];
  const float* w1s = (const float*)d_in[14];
  const float* w2s = (const float*)d_in[15];
  const float* g2  = (const float*)d_in[16];
  const float* b2  = (const float*)d_in[17];
  float* out = (float*)d_out;

  char* ws = (char*)d_ws;
  size_t off = 0;
  auto alloc = [&](size_t bytes) -> char* {
    char* p = ws + off;
    off += (bytes + 255) & ~(size_t)255;
    return p;
  };
  short* Xb   = (short*)alloc((size_t)MROWS * DMODEL * 2);   // X bf16; then h bf16
  short* Wqkv = (short*)alloc((size_t)QKVN * DMODEL * 2);    // [3072][1024]
  short* W1   = (short*)alloc((size_t)DFF * DMODEL * 2);
  short* W2   = (short*)alloc((size_t)DMODEL * DFF * 2);
  short* Wv   = Wqkv + (size_t)2 * DMODEL * DMODEL;          // V weights within Wqkv
  short* QKVb = (short*)alloc((size_t)MROWS * QKVN * 2);     // [4096][3072], 24MB
  short* AVb  = (short*)alloc((size_t)MROWS * DMODEL * 2);   // 8MB, contiguous after QKVb
  float* tmpF = (float*)alloc((size_t)MROWS * DMODEL * 4);
  float* hF   = (float*)alloc((size_t)MROWS * DMODEL * 4);
  double* acc = (double*)alloc(256);
  short* L1 = QKVb;  // reuse QKVb+AVb region (32MB) for l1 [4096][4096] bf16

  hipMemsetAsync(acc, 0, 16, stream);

  // casts (+ fused KL on the weight tensors)
  cast_kernel<<<MROWS * DMODEL / 1024, 256, 0, stream>>>(dec, Xb, MROWS * DMODEL);
  cast_kl_kernel<<<1024, 256, 0, stream>>>(qm, qs, Wqkv, DMODEL * DMODEL, acc);
  cast_kl_kernel<<<1024, 256, 0, stream>>>(km, ks, Wqkv + (size_t)DMODEL * DMODEL, DMODEL * DMODEL, acc);
  cast_kl_kernel<<<1024, 256, 0, stream>>>(vm, vs, Wqkv + (size_t)2 * DMODEL * DMODEL, DMODEL * DMODEL, acc);
  cast_kl_kernel<<<1024, 256, 0, stream>>>(om, os_, nullptr, DMODEL * DMODEL, acc);
  cast_kl_kernel<<<1024, 256, 0, stream>>>(w1m, w1s, W1, DFF * DMODEL, acc + 1);
  cast_kl_kernel<<<1024, 256, 0, stream>>>(w2m, w2s, W2, DMODEL * DFF, acc + 1);

  // fused QKV projection: [4096][3072] = Xb[4096][1024] @ Wqkv^T
  gemm_bt<128><<<(QKVN / 128) * (MROWS / 128), 512, 0, stream>>>(Xb, Wqkv, nullptr, QKVb, MROWS, QKVN, DMODEL, QKVN / 128);

  // attention
  attn_kernel<<<dim3(16, BATCH * NHEADS), 256, 0, stream>>>(QKVb, AVb);

  // attn output projection (bug-faithful: uses value_mean); BN=64 -> 512 blocks
  gemm_bt<64><<<(DMODEL / 64) * (MROWS / 128), 512, 0, stream>>>(AVb, Wv, tmpF, nullptr, MROWS, DMODEL, DMODEL, DMODEL / 64);

  // LN1: h = LN(dec + attn_out) -> hF (f32) + Xb (bf16)
  ln_kernel<<<MROWS, 256, 0, stream>>>(dec, tmpF, g1, b1, hF, Xb);

  // FF
  gemm_bt<128><<<(DFF / 128) * (MROWS / 128), 512, 0, stream>>>(Xb, W1, nullptr, L1, MROWS, DFF, DMODEL, DFF / 128);
  gemm_bt<64><<<(DMODEL / 64) * (MROWS / 128), 512, 0, stream>>>(L1, W2, tmpF, nullptr, MROWS, DMODEL, DFF, DMODEL / 64);

  // LN2 -> final out
  ln_kernel<<<MROWS, 256, 0, stream>>>(hF, tmpF, g2, b2, out, nullptr);

  // KL finalize
  kl_final<<<1, 1, 0, stream>>>(acc, out + (size_t)MROWS * DMODEL);
}